// Round 7
// baseline (453.411 us; speedup 1.0000x reference)
//
#include <hip/hip_runtime.h>

// Bahdanau additive attention, S=T=512, DU=DT=512, D=1024, fp32.
// score[t,s] = b_s + sum_d w[d]*tanh(A[s,d]+B[t,d]);  out = softmax_s(score) @ rnn
// tanh(x) = 1 - 2/(exp(2x)+1); const shift drops under softmax.
// exp2(C2*(a+b)) = EA[s,d]*EB[t,d]  (EA,EB precomputed in k1/k1b epilogues).
// k2 batches 4 d-steps into ONE rcp:  sum_i w_i/e_i = N/(e0 e1 e2 e3), exact.
// Split ws layout (floats): A0|A1|B0|B1 (4x512K) | P[8][256K] | wgt[256K] = 17.8 MB
// Fallback layout: A|B|P[8]|wgt = 13.6 MB, no K-split.

#define C2F 2.8853900817779268f   // 2*log2(e)

// ---- k1: partial GEMM. i in [0,1024): i<512 -> A (in=rnn), else B (in=tgt, +bias).
// 64x64 tile, 4x4 micro, k-chunk 32, K split ksplit ways via blockIdx.z.
// doexp!=0 (no-split path): epilogue writes exp2(C2*(acc+bias)) directly.
__global__ __launch_bounds__(256, 4) void k1_gemm_ab(
    const float* __restrict__ rnn, const float* __restrict__ tgt,
    const float* __restrict__ W, const float* __restrict__ bl,
    float* __restrict__ Abuf, float* __restrict__ Bbuf, int ksplit, int doexp)
{
    __shared__ float xt[32][68];   // [k][i]
    __shared__ float wt[32][68];   // [k][j]
    const int j0 = blockIdx.x * 64;
    const int i0 = blockIdx.y * 64;
    const int kz = blockIdx.z;
    const int klen = 512 / ksplit;
    const int kbase = kz * klen;
    const bool isB = (i0 >= 512);
    const float* __restrict__ in = isB ? tgt : rnn;
    const int irow0 = isB ? (i0 - 512) : i0;
    const int koff = isB ? 512 : 0;
    const int tid = threadIdx.x;
    const int lrow = tid >> 2;     // 0..63
    const int kq   = tid & 3;      // k offset = kq*8
    const int ti   = tid >> 4;     // 0..15 -> i micro base ti*4
    const int tj   = tid & 15;     // 0..15 -> j micro base tj*4
    const float* __restrict__ inp = in + (size_t)(irow0 + lrow) * 512 + kbase + kq * 8;
    const float* __restrict__ wp  = W  + (size_t)(j0 + lrow) * 1024 + koff + kbase + kq * 8;
    float acc[4][4] = {};
    float4 x0 = *(const float4*)(inp);
    float4 x1 = *(const float4*)(inp + 4);
    float4 w0 = *(const float4*)(wp);
    float4 w1 = *(const float4*)(wp + 4);
    for (int k0 = 0; k0 < klen; k0 += 32) {
        __syncthreads();
        xt[kq*8+0][lrow] = x0.x; xt[kq*8+1][lrow] = x0.y; xt[kq*8+2][lrow] = x0.z; xt[kq*8+3][lrow] = x0.w;
        xt[kq*8+4][lrow] = x1.x; xt[kq*8+5][lrow] = x1.y; xt[kq*8+6][lrow] = x1.z; xt[kq*8+7][lrow] = x1.w;
        wt[kq*8+0][lrow] = w0.x; wt[kq*8+1][lrow] = w0.y; wt[kq*8+2][lrow] = w0.z; wt[kq*8+3][lrow] = w0.w;
        wt[kq*8+4][lrow] = w1.x; wt[kq*8+5][lrow] = w1.y; wt[kq*8+6][lrow] = w1.z; wt[kq*8+7][lrow] = w1.w;
        __syncthreads();
        if (k0 + 32 < klen) {
            x0 = *(const float4*)(inp + k0 + 32);
            x1 = *(const float4*)(inp + k0 + 36);
            w0 = *(const float4*)(wp + k0 + 32);
            w1 = *(const float4*)(wp + k0 + 36);
        }
        #pragma unroll
        for (int k = 0; k < 32; ++k) {
            const float4 av = *(const float4*)&xt[k][ti * 4];
            const float4 bv = *(const float4*)&wt[k][tj * 4];
            const float ar[4] = {av.x, av.y, av.z, av.w};
            const float br[4] = {bv.x, bv.y, bv.z, bv.w};
            #pragma unroll
            for (int r = 0; r < 4; ++r)
                #pragma unroll
                for (int c = 0; c < 4; ++c)
                    acc[r][c] = __builtin_fmaf(ar[r], br[c], acc[r][c]);
        }
    }
    float4 bq = make_float4(0.f, 0.f, 0.f, 0.f);
    if (isB && kz == ksplit - 1) bq = *(const float4*)(bl + j0 + tj * 4);
    float* __restrict__ dst = (isB ? Bbuf : Abuf) + (size_t)kz * 524288;
    #pragma unroll
    for (int r = 0; r < 4; ++r) {
        float4 o;
        o.x = (acc[r][0] + bq.x) * C2F;
        o.y = (acc[r][1] + bq.y) * C2F;
        o.z = (acc[r][2] + bq.z) * C2F;
        o.w = (acc[r][3] + bq.w) * C2F;
        if (doexp) {
            o.x = __builtin_amdgcn_exp2f(o.x);
            o.y = __builtin_amdgcn_exp2f(o.y);
            o.z = __builtin_amdgcn_exp2f(o.z);
            o.w = __builtin_amdgcn_exp2f(o.w);
        }
        *(float4*)(dst + (size_t)(irow0 + ti * 4 + r) * 1024 + j0 + tj * 4) = o;
    }
}

// ---- k1b: A0 = exp2(A0+A1); B0 = exp2(B0+B1) (split path only) ----
__global__ __launch_bounds__(256, 4) void k1b_sum(float* __restrict__ ws4)
{
    const int i = (blockIdx.x * 256 + threadIdx.x) * 4;
    const float4 a0 = *(const float4*)(ws4 + i);
    const float4 a1 = *(const float4*)(ws4 + 524288 + i);
    const float4 b0 = *(const float4*)(ws4 + 2 * 524288 + i);
    const float4 b1 = *(const float4*)(ws4 + 3 * 524288 + i);
    float4 a, b;
    a.x = __builtin_amdgcn_exp2f(a0.x + a1.x);
    a.y = __builtin_amdgcn_exp2f(a0.y + a1.y);
    a.z = __builtin_amdgcn_exp2f(a0.z + a1.z);
    a.w = __builtin_amdgcn_exp2f(a0.w + a1.w);
    b.x = __builtin_amdgcn_exp2f(b0.x + b1.x);
    b.y = __builtin_amdgcn_exp2f(b0.y + b1.y);
    b.z = __builtin_amdgcn_exp2f(b0.z + b1.z);
    b.w = __builtin_amdgcn_exp2f(b0.w + b1.w);
    *(float4*)(ws4 + i) = a;
    *(float4*)(ws4 + 2 * 524288 + i) = b;
}

// ---- k2 (hot): P[z][t][s] = sum_{d in chunk z} w[d] / (EA[s,d]*EB[t,d] + 1) ----
// 64x64 (t,s) tile, 4x4 micro, d split 8 ways. 4 d-steps share one rcp:
// sum_i w_i/e_i = ((w0 e1 + w1 e0) e2 e3 + (w2 e3 + w3 e2) e0 e1) / (e0 e1 e2 e3).
__global__ __launch_bounds__(256, 4) void k2_scores(
    const float* __restrict__ EA, const float* __restrict__ EB,
    const float* __restrict__ wsc, float* __restrict__ P, int dchunk)
{
    __shared__ float at[32][68];   // [d][s]
    __shared__ float bt[32][68];   // [d][t]
    __shared__ float wl[128];
    const int s0 = blockIdx.x * 64;
    const int t0 = blockIdx.y * 64;
    const int dz = blockIdx.z * dchunk;
    const int tid = threadIdx.x;
    if (tid < dchunk) wl[tid] = wsc[dz + tid];
    const int srow = tid & 63;     // staging row (lane-major: conflict-free writes)
    const int kq   = tid >> 6;     // wave-uniform 0..3, d-offset kq*8
    const int ti   = tid >> 4;     // 0..15 -> t micro base ti*4
    const int tj   = tid & 15;     // 0..15 -> s micro base tj*4
    const float* __restrict__ Arow = EA + (size_t)(s0 + srow) * 1024 + dz + kq * 8;
    const float* __restrict__ Brow = EB + (size_t)(t0 + srow) * 1024 + dz + kq * 8;
    float acc[4][4] = {};
    float4 pa0 = *(const float4*)(Arow);
    float4 pa1 = *(const float4*)(Arow + 4);
    float4 pb0 = *(const float4*)(Brow);
    float4 pb1 = *(const float4*)(Brow + 4);
    for (int d0 = 0; d0 < dchunk; d0 += 32) {
        __syncthreads();
        at[kq*8+0][srow] = pa0.x; at[kq*8+1][srow] = pa0.y; at[kq*8+2][srow] = pa0.z; at[kq*8+3][srow] = pa0.w;
        at[kq*8+4][srow] = pa1.x; at[kq*8+5][srow] = pa1.y; at[kq*8+6][srow] = pa1.z; at[kq*8+7][srow] = pa1.w;
        bt[kq*8+0][srow] = pb0.x; bt[kq*8+1][srow] = pb0.y; bt[kq*8+2][srow] = pb0.z; bt[kq*8+3][srow] = pb0.w;
        bt[kq*8+4][srow] = pb1.x; bt[kq*8+5][srow] = pb1.y; bt[kq*8+6][srow] = pb1.z; bt[kq*8+7][srow] = pb1.w;
        __syncthreads();
        if (d0 + 32 < dchunk) {
            pa0 = *(const float4*)(Arow + d0 + 32);
            pa1 = *(const float4*)(Arow + d0 + 36);
            pb0 = *(const float4*)(Brow + d0 + 32);
            pb1 = *(const float4*)(Brow + d0 + 36);
        }
        #pragma unroll
        for (int dd = 0; dd < 32; dd += 4) {
            const float4 wa = *(const float4*)&wl[d0 + dd];
            const float4 A0 = *(const float4*)&at[dd + 0][tj * 4];
            const float4 A1 = *(const float4*)&at[dd + 1][tj * 4];
            const float4 A2 = *(const float4*)&at[dd + 2][tj * 4];
            const float4 A3 = *(const float4*)&at[dd + 3][tj * 4];
            const float4 B0 = *(const float4*)&bt[dd + 0][ti * 4];
            const float4 B1 = *(const float4*)&bt[dd + 1][ti * 4];
            const float4 B2 = *(const float4*)&bt[dd + 2][ti * 4];
            const float4 B3 = *(const float4*)&bt[dd + 3][ti * 4];
            const float aC[4][4] = {{A0.x,A0.y,A0.z,A0.w},{A1.x,A1.y,A1.z,A1.w},
                                    {A2.x,A2.y,A2.z,A2.w},{A3.x,A3.y,A3.z,A3.w}};
            const float bR[4][4] = {{B0.x,B0.y,B0.z,B0.w},{B1.x,B1.y,B1.z,B1.w},
                                    {B2.x,B2.y,B2.z,B2.w},{B3.x,B3.y,B3.z,B3.w}};
            #pragma unroll
            for (int r = 0; r < 4; ++r) {
                #pragma unroll
                for (int c = 0; c < 4; ++c) {
                    const float e0 = __builtin_fmaf(aC[0][c], bR[0][r], 1.f);
                    const float e1 = __builtin_fmaf(aC[1][c], bR[1][r], 1.f);
                    const float e2 = __builtin_fmaf(aC[2][c], bR[2][r], 1.f);
                    const float e3 = __builtin_fmaf(aC[3][c], bR[3][r], 1.f);
                    const float l01 = e0 * e1;
                    const float l23 = e2 * e3;
                    const float n01 = __builtin_fmaf(wa.x, e1, wa.y * e0);
                    const float n23 = __builtin_fmaf(wa.z, e3, wa.w * e2);
                    const float N = __builtin_fmaf(n01, l23, n23 * l01);
                    acc[r][c] = __builtin_fmaf(N, __builtin_amdgcn_rcpf(l01 * l23), acc[r][c]);
                }
            }
        }
    }
    float* __restrict__ Pz = P + (size_t)blockIdx.z * 512 * 512;
    #pragma unroll
    for (int r = 0; r < 4; ++r) {
        float4 o;
        o.x = acc[r][0]; o.y = acc[r][1]; o.z = acc[r][2]; o.w = acc[r][3];
        *(float4*)(Pz + (size_t)(t0 + ti * 4 + r) * 512 + s0 + tj * 4) = o;
    }
}

// ---- k3: weights[t][:] = softmax_s( -2 * sum_z P_z[t][:] ) ----
__global__ __launch_bounds__(256, 4) void k3_softmax(
    const float* __restrict__ P, float* __restrict__ wgt, int nz)
{
    __shared__ float wm[4];
    __shared__ float wsum[4];
    const int t = blockIdx.x;
    const int tid = threadIdx.x;
    const size_t base = (size_t)t * 512 + tid * 2;
    float sx = 0.f, sy = 0.f;
    for (int z = 0; z < nz; ++z) {
        const float2 p = *(const float2*)(P + base + (size_t)z * 262144);
        sx += p.x; sy += p.y;
    }
    const float x0 = -2.f * sx;
    const float x1 = -2.f * sy;
    float m = fmaxf(x0, x1);
    #pragma unroll
    for (int off = 32; off; off >>= 1) m = fmaxf(m, __shfl_xor(m, off));
    if ((tid & 63) == 0) wm[tid >> 6] = m;
    __syncthreads();
    m = fmaxf(fmaxf(wm[0], wm[1]), fmaxf(wm[2], wm[3]));
    const float L2E = 1.4426950408889634f;
    const float e0 = __builtin_amdgcn_exp2f((x0 - m) * L2E);
    const float e1 = __builtin_amdgcn_exp2f((x1 - m) * L2E);
    float s = e0 + e1;
    #pragma unroll
    for (int off = 32; off; off >>= 1) s += __shfl_xor(s, off);
    if ((tid & 63) == 0) wsum[tid >> 6] = s;
    __syncthreads();
    s = wsum[0] + wsum[1] + wsum[2] + wsum[3];
    const float inv = 1.0f / s;
    float2 o; o.x = e0 * inv; o.y = e1 * inv;
    *(float2*)(wgt + (size_t)t * 512 + tid * 2) = o;
}

// ---- k4: P4[z] = wgt[:, z*64:(z+1)*64] @ rnn[z*64:(z+1)*64, :] ----
// 64x64 (t,d) tile, 4x4 micro, K split 8 ways via blockIdx.z.
__global__ __launch_bounds__(256, 4) void k4_out(
    const float* __restrict__ wgt, const float* __restrict__ rnn,
    float* __restrict__ P4)
{
    __shared__ float wtt[32][68];  // [s][t]
    __shared__ float rn[32][68];   // [s][d]
    const int d0g = blockIdx.x * 64;
    const int t0g = blockIdx.y * 64;
    const int z   = blockIdx.z;
    const int tid = threadIdx.x;
    const int trow = tid & 63;     // wgt staging row (lane-major)
    const int kq   = tid >> 6;     // wave-uniform, s-offset kq*8
    const int srw  = tid & 31;     // rnn staging row
    const int cq   = tid >> 5;     // 0..7, d-col offset cq*8
    const int ti = tid >> 4, tj = tid & 15;
    float acc[4][4] = {};
    for (int sc = z * 64; sc < z * 64 + 64; sc += 32) {
        const float4 w0 = *(const float4*)(wgt + (size_t)(t0g + trow) * 512 + sc + kq * 8);
        const float4 w1 = *(const float4*)(wgt + (size_t)(t0g + trow) * 512 + sc + kq * 8 + 4);
        const float4 r0 = *(const float4*)(rnn + (size_t)(sc + srw) * 512 + d0g + cq * 8);
        const float4 r1 = *(const float4*)(rnn + (size_t)(sc + srw) * 512 + d0g + cq * 8 + 4);
        __syncthreads();
        wtt[kq*8+0][trow] = w0.x; wtt[kq*8+1][trow] = w0.y; wtt[kq*8+2][trow] = w0.z; wtt[kq*8+3][trow] = w0.w;
        wtt[kq*8+4][trow] = w1.x; wtt[kq*8+5][trow] = w1.y; wtt[kq*8+6][trow] = w1.z; wtt[kq*8+7][trow] = w1.w;
        *(float4*)&rn[srw][cq * 8]     = r0;
        *(float4*)&rn[srw][cq * 8 + 4] = r1;
        __syncthreads();
        #pragma unroll
        for (int s = 0; s < 32; ++s) {
            const float4 av = *(const float4*)&wtt[s][ti * 4];
            const float4 bv = *(const float4*)&rn[s][tj * 4];
            const float ar[4] = {av.x, av.y, av.z, av.w};
            const float bc[4] = {bv.x, bv.y, bv.z, bv.w};
            #pragma unroll
            for (int r = 0; r < 4; ++r)
                #pragma unroll
                for (int c = 0; c < 4; ++c)
                    acc[r][c] = __builtin_fmaf(ar[r], bc[c], acc[r][c]);
        }
    }
    float* __restrict__ Pz = P4 + (size_t)z * 262144;
    #pragma unroll
    for (int r = 0; r < 4; ++r) {
        float4 o;
        o.x = acc[r][0]; o.y = acc[r][1]; o.z = acc[r][2]; o.w = acc[r][3];
        *(float4*)(Pz + (size_t)(t0g + ti * 4 + r) * 512 + d0g + tj * 4) = o;
    }
}

// ---- k5: out = sum_{z=0..7} P4[z] ----
__global__ __launch_bounds__(256, 4) void k5_reduce(
    const float* __restrict__ P4, float* __restrict__ out)
{
    const int i = (blockIdx.x * 256 + threadIdx.x) * 4;
    float4 a = *(const float4*)(P4 + i);
    #pragma unroll
    for (int z = 1; z < 8; ++z) {
        const float4 b = *(const float4*)(P4 + (size_t)z * 262144 + i);
        a.x += b.x; a.y += b.y; a.z += b.z; a.w += b.w;
    }
    *(float4*)(out + i) = a;
}

extern "C" void kernel_launch(void* const* d_in, const int* in_sizes, int n_in,
                              void* d_out, int out_size, void* d_ws, size_t ws_size,
                              hipStream_t stream) {
    const float* rnn = (const float*)d_in[0];
    const float* tgt = (const float*)d_in[1];
    const float* W   = (const float*)d_in[2];
    const float* bl  = (const float*)d_in[3];
    const float* wsc = (const float*)d_in[4];
    // d_in[5] (b_score): constant shift under softmax -> unused.
    float* out = (float*)d_out;

    const int nz = 8;
    const int dchunk = 1024 / nz;   // 128
    float* ws = (float*)d_ws;

    // Split path: A0|A1|B0|B1|P[8]|wgt = (4*524288 + 8*262144 + 262144)*4 = 17,825,792 B
    const bool split = (ws_size >= 17825792u);

    if (split) {
        float* A   = ws;                         // becomes EA after k1b
        float* B   = ws + 2 * 524288;            // becomes EB after k1b
        float* P   = ws + 4 * 524288;
        float* wgt = P + (size_t)nz * 262144;
        float* P4  = P;                          // alias: P dead after k3
        k1_gemm_ab<<<dim3(16, 16, 2), 256, 0, stream>>>(rnn, tgt, W, bl, A, B, 2, 0);
        k1b_sum   <<<512,             256, 0, stream>>>(ws);
        k2_scores <<<dim3(8, 8, nz),  256, 0, stream>>>(A, B, wsc, P, dchunk);
        k3_softmax<<<512,             256, 0, stream>>>(P, wgt, nz);
        k4_out    <<<dim3(8, 8, 8),   256, 0, stream>>>(wgt, rnn, P4);
        k5_reduce <<<256,             256, 0, stream>>>(P4, out);
    } else {
        // Fallback: A|B|P[8]|wgt = 13,631,488 B, no K-split; k1 applies exp2 itself.
        float* A   = ws;
        float* B   = ws + 524288;
        float* P   = ws + 2 * 524288;
        float* wgt = P + (size_t)nz * 262144;
        float* P4  = P;
        k1_gemm_ab<<<dim3(16, 16, 1), 256, 0, stream>>>(rnn, tgt, W, bl, A, B, 1, 1);
        k2_scores <<<dim3(8, 8, nz),  256, 0, stream>>>(A, B, wsc, P, dchunk);
        k3_softmax<<<512,             256, 0, stream>>>(P, wgt, nz);
        k4_out    <<<dim3(8, 8, 8),   256, 0, stream>>>(wgt, rnn, P4);
        k5_reduce <<<256,             256, 0, stream>>>(P4, out);
    }
}

// Round 8
// 69.500 us; speedup vs baseline: 6.5239x; 6.5239x over previous
//
#include <hip/hip_runtime.h>

// Bahdanau additive attention, S=T=512, DU=DT=512, D=1024, fp32.
// score[t,s] = b_s + sum_d w[d]*tanh(A[s,d]+B[t,d]);  out = softmax_s(score) @ rnn
// tanh(x) = 1 - 2/(exp(2x)+1); const shift drops under softmax.
// exp2(C2*(a+b)) = EA[s,d]*EB[t,d]  (EA,EB precomputed in k1/k1b epilogues).
// k2 batches 4 d-steps into ONE rcp:  sum_i w_i/e_i = N/(e0 e1 e2 e3), exact.
// R7 lesson (rule #20): k2's cell loop must use NAMED SCALARS ONLY — runtime-indexed
// local arrays go to scratch (1.7 GB HBM traffic, 12x slowdown).
// Split ws layout (floats): A0|A1|B0|B1 (4x512K) | P[8][256K] | wgt[256K] = 17.8 MB
// Fallback layout: A|B|P[8]|wgt = 13.6 MB, no K-split.

#define C2F 2.8853900817779268f   // 2*log2(e)

// ---- k1: partial GEMM. i in [0,1024): i<512 -> A (in=rnn), else B (in=tgt, +bias).
__global__ __launch_bounds__(256, 4) void k1_gemm_ab(
    const float* __restrict__ rnn, const float* __restrict__ tgt,
    const float* __restrict__ W, const float* __restrict__ bl,
    float* __restrict__ Abuf, float* __restrict__ Bbuf, int ksplit, int doexp)
{
    __shared__ float xt[32][68];   // [k][i]
    __shared__ float wt[32][68];   // [k][j]
    const int j0 = blockIdx.x * 64;
    const int i0 = blockIdx.y * 64;
    const int kz = blockIdx.z;
    const int klen = 512 / ksplit;
    const int kbase = kz * klen;
    const bool isB = (i0 >= 512);
    const float* __restrict__ in = isB ? tgt : rnn;
    const int irow0 = isB ? (i0 - 512) : i0;
    const int koff = isB ? 512 : 0;
    const int tid = threadIdx.x;
    const int lrow = tid >> 2;     // 0..63
    const int kq   = tid & 3;      // k offset = kq*8
    const int ti   = tid >> 4;     // 0..15 -> i micro base ti*4
    const int tj   = tid & 15;     // 0..15 -> j micro base tj*4
    const float* __restrict__ inp = in + (size_t)(irow0 + lrow) * 512 + kbase + kq * 8;
    const float* __restrict__ wp  = W  + (size_t)(j0 + lrow) * 1024 + koff + kbase + kq * 8;
    float acc[4][4] = {};
    float4 x0 = *(const float4*)(inp);
    float4 x1 = *(const float4*)(inp + 4);
    float4 w0 = *(const float4*)(wp);
    float4 w1 = *(const float4*)(wp + 4);
    for (int k0 = 0; k0 < klen; k0 += 32) {
        __syncthreads();
        xt[kq*8+0][lrow] = x0.x; xt[kq*8+1][lrow] = x0.y; xt[kq*8+2][lrow] = x0.z; xt[kq*8+3][lrow] = x0.w;
        xt[kq*8+4][lrow] = x1.x; xt[kq*8+5][lrow] = x1.y; xt[kq*8+6][lrow] = x1.z; xt[kq*8+7][lrow] = x1.w;
        wt[kq*8+0][lrow] = w0.x; wt[kq*8+1][lrow] = w0.y; wt[kq*8+2][lrow] = w0.z; wt[kq*8+3][lrow] = w0.w;
        wt[kq*8+4][lrow] = w1.x; wt[kq*8+5][lrow] = w1.y; wt[kq*8+6][lrow] = w1.z; wt[kq*8+7][lrow] = w1.w;
        __syncthreads();
        if (k0 + 32 < klen) {
            x0 = *(const float4*)(inp + k0 + 32);
            x1 = *(const float4*)(inp + k0 + 36);
            w0 = *(const float4*)(wp + k0 + 32);
            w1 = *(const float4*)(wp + k0 + 36);
        }
        #pragma unroll
        for (int k = 0; k < 32; ++k) {
            const float4 av = *(const float4*)&xt[k][ti * 4];
            const float4 bv = *(const float4*)&wt[k][tj * 4];
            const float ar[4] = {av.x, av.y, av.z, av.w};
            const float br[4] = {bv.x, bv.y, bv.z, bv.w};
            #pragma unroll
            for (int r = 0; r < 4; ++r)
                #pragma unroll
                for (int c = 0; c < 4; ++c)
                    acc[r][c] = __builtin_fmaf(ar[r], br[c], acc[r][c]);
        }
    }
    float4 bq = make_float4(0.f, 0.f, 0.f, 0.f);
    if (isB && kz == ksplit - 1) bq = *(const float4*)(bl + j0 + tj * 4);
    float* __restrict__ dst = (isB ? Bbuf : Abuf) + (size_t)kz * 524288;
    #pragma unroll
    for (int r = 0; r < 4; ++r) {
        float4 o;
        o.x = (acc[r][0] + bq.x) * C2F;
        o.y = (acc[r][1] + bq.y) * C2F;
        o.z = (acc[r][2] + bq.z) * C2F;
        o.w = (acc[r][3] + bq.w) * C2F;
        if (doexp) {
            o.x = __builtin_amdgcn_exp2f(o.x);
            o.y = __builtin_amdgcn_exp2f(o.y);
            o.z = __builtin_amdgcn_exp2f(o.z);
            o.w = __builtin_amdgcn_exp2f(o.w);
        }
        *(float4*)(dst + (size_t)(irow0 + ti * 4 + r) * 1024 + j0 + tj * 4) = o;
    }
}

// ---- k1b: A0 = exp2(A0+A1); B0 = exp2(B0+B1) (split path only) ----
__global__ __launch_bounds__(256, 4) void k1b_sum(float* __restrict__ ws4)
{
    const int i = (blockIdx.x * 256 + threadIdx.x) * 4;
    const float4 a0 = *(const float4*)(ws4 + i);
    const float4 a1 = *(const float4*)(ws4 + 524288 + i);
    const float4 b0 = *(const float4*)(ws4 + 2 * 524288 + i);
    const float4 b1 = *(const float4*)(ws4 + 3 * 524288 + i);
    float4 a, b;
    a.x = __builtin_amdgcn_exp2f(a0.x + a1.x);
    a.y = __builtin_amdgcn_exp2f(a0.y + a1.y);
    a.z = __builtin_amdgcn_exp2f(a0.z + a1.z);
    a.w = __builtin_amdgcn_exp2f(a0.w + a1.w);
    b.x = __builtin_amdgcn_exp2f(b0.x + b1.x);
    b.y = __builtin_amdgcn_exp2f(b0.y + b1.y);
    b.z = __builtin_amdgcn_exp2f(b0.z + b1.z);
    b.w = __builtin_amdgcn_exp2f(b0.w + b1.w);
    *(float4*)(ws4 + i) = a;
    *(float4*)(ws4 + 2 * 524288 + i) = b;
}

// ---- k2 (hot): P[z][t][s] = sum_{d in chunk z} w[d] / (EA[s,d]*EB[t,d] + 1) ----
// 64x64 (t,s) tile, 4x4 micro, d split 8 ways. 4 d-steps share ONE rcp.
// ALL named scalars — no local arrays (rule #20).
#define K2CELL(ACC, CC, RR) do {                                         \
    const float e0_ = __builtin_fmaf(A0.CC, B0.RR, 1.f);                 \
    const float e1_ = __builtin_fmaf(A1.CC, B1.RR, 1.f);                 \
    const float e2_ = __builtin_fmaf(A2.CC, B2.RR, 1.f);                 \
    const float e3_ = __builtin_fmaf(A3.CC, B3.RR, 1.f);                 \
    const float l01_ = e0_ * e1_;                                        \
    const float l23_ = e2_ * e3_;                                        \
    const float n01_ = __builtin_fmaf(wa.x, e1_, wa.y * e0_);            \
    const float n23_ = __builtin_fmaf(wa.z, e3_, wa.w * e2_);            \
    const float N_ = __builtin_fmaf(n01_, l23_, n23_ * l01_);            \
    ACC = __builtin_fmaf(N_, __builtin_amdgcn_rcpf(l01_ * l23_), ACC);   \
} while (0)

__global__ __launch_bounds__(256, 4) void k2_scores(
    const float* __restrict__ EA, const float* __restrict__ EB,
    const float* __restrict__ wsc, float* __restrict__ P, int dchunk)
{
    __shared__ float at[32][68];   // [d][s]
    __shared__ float bt[32][68];   // [d][t]
    __shared__ float wl[128];
    const int s0 = blockIdx.x * 64;
    const int t0 = blockIdx.y * 64;
    const int dz = blockIdx.z * dchunk;
    const int tid = threadIdx.x;
    if (tid < dchunk) wl[tid] = wsc[dz + tid];
    const int srow = tid & 63;     // staging row (lane-major: conflict-free writes)
    const int kq   = tid >> 6;     // wave-uniform 0..3, d-offset kq*8
    const int ti   = tid >> 4;     // 0..15 -> t micro base ti*4
    const int tj   = tid & 15;     // 0..15 -> s micro base tj*4
    const float* __restrict__ Arow = EA + (size_t)(s0 + srow) * 1024 + dz + kq * 8;
    const float* __restrict__ Brow = EB + (size_t)(t0 + srow) * 1024 + dz + kq * 8;
    float4 acc0 = make_float4(0.f,0.f,0.f,0.f);   // r=0, components = c
    float4 acc1 = make_float4(0.f,0.f,0.f,0.f);
    float4 acc2 = make_float4(0.f,0.f,0.f,0.f);
    float4 acc3 = make_float4(0.f,0.f,0.f,0.f);
    float4 pa0 = *(const float4*)(Arow);
    float4 pa1 = *(const float4*)(Arow + 4);
    float4 pb0 = *(const float4*)(Brow);
    float4 pb1 = *(const float4*)(Brow + 4);
    for (int d0 = 0; d0 < dchunk; d0 += 32) {
        __syncthreads();
        at[kq*8+0][srow] = pa0.x; at[kq*8+1][srow] = pa0.y; at[kq*8+2][srow] = pa0.z; at[kq*8+3][srow] = pa0.w;
        at[kq*8+4][srow] = pa1.x; at[kq*8+5][srow] = pa1.y; at[kq*8+6][srow] = pa1.z; at[kq*8+7][srow] = pa1.w;
        bt[kq*8+0][srow] = pb0.x; bt[kq*8+1][srow] = pb0.y; bt[kq*8+2][srow] = pb0.z; bt[kq*8+3][srow] = pb0.w;
        bt[kq*8+4][srow] = pb1.x; bt[kq*8+5][srow] = pb1.y; bt[kq*8+6][srow] = pb1.z; bt[kq*8+7][srow] = pb1.w;
        __syncthreads();
        if (d0 + 32 < dchunk) {
            pa0 = *(const float4*)(Arow + d0 + 32);
            pa1 = *(const float4*)(Arow + d0 + 36);
            pb0 = *(const float4*)(Brow + d0 + 32);
            pb1 = *(const float4*)(Brow + d0 + 36);
        }
        for (int dd = 0; dd < 32; dd += 4) {   // runtime dd OK: LDS addr math only
            const float4 wa = *(const float4*)&wl[d0 + dd];
            const float4 A0 = *(const float4*)&at[dd + 0][tj * 4];
            const float4 A1 = *(const float4*)&at[dd + 1][tj * 4];
            const float4 A2 = *(const float4*)&at[dd + 2][tj * 4];
            const float4 A3 = *(const float4*)&at[dd + 3][tj * 4];
            const float4 B0 = *(const float4*)&bt[dd + 0][ti * 4];
            const float4 B1 = *(const float4*)&bt[dd + 1][ti * 4];
            const float4 B2 = *(const float4*)&bt[dd + 2][ti * 4];
            const float4 B3 = *(const float4*)&bt[dd + 3][ti * 4];
            K2CELL(acc0.x, x, x); K2CELL(acc0.y, y, x); K2CELL(acc0.z, z, x); K2CELL(acc0.w, w, x);
            K2CELL(acc1.x, x, y); K2CELL(acc1.y, y, y); K2CELL(acc1.z, z, y); K2CELL(acc1.w, w, y);
            K2CELL(acc2.x, x, z); K2CELL(acc2.y, y, z); K2CELL(acc2.z, z, z); K2CELL(acc2.w, w, z);
            K2CELL(acc3.x, x, w); K2CELL(acc3.y, y, w); K2CELL(acc3.z, z, w); K2CELL(acc3.w, w, w);
        }
    }
    float* __restrict__ Pz = P + (size_t)blockIdx.z * 512 * 512;
    *(float4*)(Pz + (size_t)(t0 + ti * 4 + 0) * 512 + s0 + tj * 4) = acc0;
    *(float4*)(Pz + (size_t)(t0 + ti * 4 + 1) * 512 + s0 + tj * 4) = acc1;
    *(float4*)(Pz + (size_t)(t0 + ti * 4 + 2) * 512 + s0 + tj * 4) = acc2;
    *(float4*)(Pz + (size_t)(t0 + ti * 4 + 3) * 512 + s0 + tj * 4) = acc3;
}

// ---- k3: weights[t][:] = softmax_s( -2 * sum_z P_z[t][:] ) ----
__global__ __launch_bounds__(256, 4) void k3_softmax(
    const float* __restrict__ P, float* __restrict__ wgt, int nz)
{
    __shared__ float wm[4];
    __shared__ float wsum[4];
    const int t = blockIdx.x;
    const int tid = threadIdx.x;
    const size_t base = (size_t)t * 512 + tid * 2;
    float sx = 0.f, sy = 0.f;
    for (int z = 0; z < nz; ++z) {
        const float2 p = *(const float2*)(P + base + (size_t)z * 262144);
        sx += p.x; sy += p.y;
    }
    const float x0 = -2.f * sx;
    const float x1 = -2.f * sy;
    float m = fmaxf(x0, x1);
    #pragma unroll
    for (int off = 32; off; off >>= 1) m = fmaxf(m, __shfl_xor(m, off));
    if ((tid & 63) == 0) wm[tid >> 6] = m;
    __syncthreads();
    m = fmaxf(fmaxf(wm[0], wm[1]), fmaxf(wm[2], wm[3]));
    const float L2E = 1.4426950408889634f;
    const float e0 = __builtin_amdgcn_exp2f((x0 - m) * L2E);
    const float e1 = __builtin_amdgcn_exp2f((x1 - m) * L2E);
    float s = e0 + e1;
    #pragma unroll
    for (int off = 32; off; off >>= 1) s += __shfl_xor(s, off);
    if ((tid & 63) == 0) wsum[tid >> 6] = s;
    __syncthreads();
    s = wsum[0] + wsum[1] + wsum[2] + wsum[3];
    const float inv = 1.0f / s;
    float2 o; o.x = e0 * inv; o.y = e1 * inv;
    *(float2*)(wgt + (size_t)t * 512 + tid * 2) = o;
}

// ---- k4: P4[z] = wgt[:, z*64:(z+1)*64] @ rnn[z*64:(z+1)*64, :] ----
__global__ __launch_bounds__(256, 4) void k4_out(
    const float* __restrict__ wgt, const float* __restrict__ rnn,
    float* __restrict__ P4)
{
    __shared__ float wtt[32][68];  // [s][t]
    __shared__ float rn[32][68];   // [s][d]
    const int d0g = blockIdx.x * 64;
    const int t0g = blockIdx.y * 64;
    const int z   = blockIdx.z;
    const int tid = threadIdx.x;
    const int trow = tid & 63;
    const int kq   = tid >> 6;
    const int srw  = tid & 31;
    const int cq   = tid >> 5;
    const int ti = tid >> 4, tj = tid & 15;
    float acc[4][4] = {};
    for (int sc = z * 64; sc < z * 64 + 64; sc += 32) {
        const float4 w0 = *(const float4*)(wgt + (size_t)(t0g + trow) * 512 + sc + kq * 8);
        const float4 w1 = *(const float4*)(wgt + (size_t)(t0g + trow) * 512 + sc + kq * 8 + 4);
        const float4 r0 = *(const float4*)(rnn + (size_t)(sc + srw) * 512 + d0g + cq * 8);
        const float4 r1 = *(const float4*)(rnn + (size_t)(sc + srw) * 512 + d0g + cq * 8 + 4);
        __syncthreads();
        wtt[kq*8+0][trow] = w0.x; wtt[kq*8+1][trow] = w0.y; wtt[kq*8+2][trow] = w0.z; wtt[kq*8+3][trow] = w0.w;
        wtt[kq*8+4][trow] = w1.x; wtt[kq*8+5][trow] = w1.y; wtt[kq*8+6][trow] = w1.z; wtt[kq*8+7][trow] = w1.w;
        *(float4*)&rn[srw][cq * 8]     = r0;
        *(float4*)&rn[srw][cq * 8 + 4] = r1;
        __syncthreads();
        #pragma unroll
        for (int s = 0; s < 32; ++s) {
            const float4 av = *(const float4*)&wtt[s][ti * 4];
            const float4 bv = *(const float4*)&rn[s][tj * 4];
            const float ar[4] = {av.x, av.y, av.z, av.w};
            const float bc[4] = {bv.x, bv.y, bv.z, bv.w};
            #pragma unroll
            for (int r = 0; r < 4; ++r)
                #pragma unroll
                for (int c = 0; c < 4; ++c)
                    acc[r][c] = __builtin_fmaf(ar[r], bc[c], acc[r][c]);
        }
    }
    float* __restrict__ Pz = P4 + (size_t)z * 262144;
    #pragma unroll
    for (int r = 0; r < 4; ++r) {
        float4 o;
        o.x = acc[r][0]; o.y = acc[r][1]; o.z = acc[r][2]; o.w = acc[r][3];
        *(float4*)(Pz + (size_t)(t0g + ti * 4 + r) * 512 + d0g + tj * 4) = o;
    }
}

// ---- k5: out = sum_{z=0..7} P4[z] ----
__global__ __launch_bounds__(256, 4) void k5_reduce(
    const float* __restrict__ P4, float* __restrict__ out)
{
    const int i = (blockIdx.x * 256 + threadIdx.x) * 4;
    float4 a = *(const float4*)(P4 + i);
    #pragma unroll
    for (int z = 1; z < 8; ++z) {
        const float4 b = *(const float4*)(P4 + (size_t)z * 262144 + i);
        a.x += b.x; a.y += b.y; a.z += b.z; a.w += b.w;
    }
    *(float4*)(out + i) = a;
}

extern "C" void kernel_launch(void* const* d_in, const int* in_sizes, int n_in,
                              void* d_out, int out_size, void* d_ws, size_t ws_size,
                              hipStream_t stream) {
    const float* rnn = (const float*)d_in[0];
    const float* tgt = (const float*)d_in[1];
    const float* W   = (const float*)d_in[2];
    const float* bl  = (const float*)d_in[3];
    const float* wsc = (const float*)d_in[4];
    // d_in[5] (b_score): constant shift under softmax -> unused.
    float* out = (float*)d_out;

    const int nz = 8;
    const int dchunk = 1024 / nz;   // 128
    float* ws = (float*)d_ws;

    const bool split = (ws_size >= 17825792u);

    if (split) {
        float* A   = ws;                         // becomes EA after k1b
        float* B   = ws + 2 * 524288;            // becomes EB after k1b
        float* P   = ws + 4 * 524288;
        float* wgt = P + (size_t)nz * 262144;
        float* P4  = P;                          // alias: P dead after k3
        k1_gemm_ab<<<dim3(16, 16, 2), 256, 0, stream>>>(rnn, tgt, W, bl, A, B, 2, 0);
        k1b_sum   <<<512,             256, 0, stream>>>(ws);
        k2_scores <<<dim3(8, 8, nz),  256, 0, stream>>>(A, B, wsc, P, dchunk);
        k3_softmax<<<512,             256, 0, stream>>>(P, wgt, nz);
        k4_out    <<<dim3(8, 8, 8),   256, 0, stream>>>(wgt, rnn, P4);
        k5_reduce <<<256,             256, 0, stream>>>(P4, out);
    } else {
        float* A   = ws;
        float* B   = ws + 524288;
        float* P   = ws + 2 * 524288;
        float* wgt = P + (size_t)nz * 262144;
        float* P4  = P;
        k1_gemm_ab<<<dim3(16, 16, 1), 256, 0, stream>>>(rnn, tgt, W, bl, A, B, 1, 1);
        k2_scores <<<dim3(8, 8, nz),  256, 0, stream>>>(A, B, wsc, P, dchunk);
        k3_softmax<<<512,             256, 0, stream>>>(P, wgt, nz);
        k4_out    <<<dim3(8, 8, 8),   256, 0, stream>>>(wgt, rnn, P4);
        k5_reduce <<<256,             256, 0, stream>>>(P4, out);
    }
}